// Round 3
// baseline (433.367 us; speedup 1.0000x reference)
//
#include <hip/hip_runtime.h>
#include <hip/hip_bf16.h>

#define NN 50000
#define NR 8
#define DIM 128
#define NE 800000
#define TM 32     // targets per block
#define CAP 1024  // per-block bucket capacity (mean 512, Poisson -> overflow prob ~0; guarded)
#define NB 1563   // ceil(NN/TM)
#define SPAD 136  // Atile row stride in bf16 (R2-proven banking for the W-phase reads)

using floatx4 = __attribute__((ext_vector_type(4))) float;
using bf16x8  = __attribute__((ext_vector_type(8))) __bf16;
using ushort8 = __attribute__((ext_vector_type(8))) unsigned short;

// ---------------- workspace layout (in floats) ----------------
// zeroed region: [0, 826160) = cnt + wsum + S2X1 + blkcnt
#define OFF_CNT   0u         // 400000: int counts, seg = t*8+r
#define OFF_WSUM  400000u    // 400000: wsum[r*NN+h] fp32 atomic accum
#define OFF_S2    800000u    // 1152: S2[1024] + X1[128] (atomic-accumulated by fused blocks)
#define OFF_BCNT  801152u    // 1563*16 ints: per-block bucket counters (64B stride)
#define OFF_BBUF  826160u    // 1563*1024 ints: per-block edge buckets, pk = (j2<<17)|head
#define OFF_XB    2426672u   // 6.4M bf16: x_emb in bf16 (16B aligned)
#define OFF_WF    5626672u   // 9*2048*8 bf16: weights in MFMA frag order
// total < 7.5M floats = 30.0 MB

// ---------------- merged prep: bf16 cast + weight frags + cnt atomics + bucket assign ----------------
// bucket key TERM-MAJOR j2 = (r<<5)|(t&31): each term-pair's edges form ONE contiguous CSR
// range inside the block -> staircase P matrix in the fused kernel.
__global__ __launch_bounds__(256) void prep_k(
    const float* __restrict__ x, __bf16* __restrict__ xb,
    const float* __restrict__ W1, const float* __restrict__ root1, __bf16* __restrict__ wf,
    const int* __restrict__ h, const int* __restrict__ r, const int* __restrict__ t,
    int* __restrict__ cnt, int* __restrict__ blkcnt, int* __restrict__ blkbuf)
{
    const int gid = blockIdx.x * 256 + threadIdx.x;
    const int nthr = gridDim.x * 256;

    if (gid < 9 * 2048) {
        int mat = gid >> 11, idx = gid & 2047;
        const float* B = (mat < 8) ? (W1 + (size_t)mat * DIM * DIM) : root1;
        int lt = idx & 63, fid = idx >> 6;
        int s = fid >> 3, nt = fid & 7;
        int n = nt * 16 + (lt & 15);
        int kb = s * 32 + (lt >> 4) * 8;
        bf16x8 v;
#pragma unroll
        for (int j = 0; j < 8; ++j) v[j] = (__bf16)B[(kb + j) * DIM + n];
        *reinterpret_cast<bf16x8*>(wf + ((size_t)mat * 2048 + idx) * 8) = v;
    }
    for (int i = gid; i < NN * DIM / 4; i += nthr) {
        int base = i * 4;
        float4 v = *reinterpret_cast<const float4*>(x + base);
        __bf16 o[4] = {(__bf16)v.x, (__bf16)v.y, (__bf16)v.z, (__bf16)v.w};
        *reinterpret_cast<uint2*>(xb + base) = *reinterpret_cast<uint2*>(o);
    }
    // edge loop: cnt atomic + bucket append (shares the h/r/t loads)
    for (int i = gid; i < NE / 4; i += nthr) {
        int base = i * 4;
        int4 hv = *reinterpret_cast<const int4*>(h + base);
        int4 rv = *reinterpret_cast<const int4*>(r + base);
        int4 tv = *reinterpret_cast<const int4*>(t + base);
#pragma unroll
        for (int j = 0; j < 4; ++j) {
            int te = (j == 0) ? tv.x : (j == 1) ? tv.y : (j == 2) ? tv.z : tv.w;
            int re = (j == 0) ? rv.x : (j == 1) ? rv.y : (j == 2) ? rv.z : rv.w;
            int he = (j == 0) ? hv.x : (j == 1) ? hv.y : (j == 2) ? hv.z : hv.w;
            atomicAdd(&cnt[te * NR + re], 1);
            int blk = te >> 5;
            int pos = atomicAdd(&blkcnt[blk * 16], 1);
            if (pos < CAP) blkbuf[blk * CAP + pos] = (((re << 5) | (te & 31)) << 17) | he;
        }
    }
}

// ---------------- wsum: 800k fire-and-forget float atomics; inv derived from cnt (no scan!) ----------------
__global__ void wsum_k(const int* __restrict__ h, const int* __restrict__ r, const int* __restrict__ t,
                       const int* __restrict__ cnt, float* __restrict__ wsum) {
    int base = (blockIdx.x * 256 + threadIdx.x) * 4;
    if (base + 3 < NE) {
        int4 hv = *reinterpret_cast<const int4*>(h + base);
        int4 rv = *reinterpret_cast<const int4*>(r + base);
        int4 tv = *reinterpret_cast<const int4*>(t + base);
        int c0 = cnt[tv.x * NR + rv.x], c1 = cnt[tv.y * NR + rv.y];
        int c2 = cnt[tv.z * NR + rv.z], c3 = cnt[tv.w * NR + rv.w];
        atomicAdd(&wsum[rv.x * NN + hv.x], 1.0f / (float)(c0 > 1 ? c0 : 1));
        atomicAdd(&wsum[rv.y * NN + hv.y], 1.0f / (float)(c1 > 1 ? c1 : 1));
        atomicAdd(&wsum[rv.z * NN + hv.z], 1.0f / (float)(c2 > 1 ? c2 : 1));
        atomicAdd(&wsum[rv.w * NN + hv.w], 1.0f / (float)(c3 > 1 ? c3 : 1));
    } else {
        for (int e = base; e < NE; ++e) {
            int c = cnt[t[e] * NR + r[e]];
            atomicAdd(&wsum[r[e] * NN + h[e]], 1.0f / (float)(c > 1 ? c : 1));
        }
    }
}

// ---------------- fused layer 1 + layer-2 partials: staircase-P MFMA aggregation ----------------
// Aggregation per 64-edge chunk is Acc[64][128] += P·E on the MFMA pipe:
//   P = 0/1 staircase (CSR-sorted edges: row g's edges = interval [loffs[g]-Cb, loffs[g+1]-Cb)),
//   A-fragment of P built IN REGISTERS from the two interval bounds (8 selects) — no LDS P.
//   E staged k-major with XOR swizzle: Et[col][e] @ element col*64 + ((e>>3)^(col>>3&7))*8 + (e&7)
//   -> paired b32 writes 2-way (free), b128 B-frag reads bank-balanced.
// Replaces R2's divergent per-lane reduce convoy (~1100cy/chunk VALU) with ~300cy of MFMA-phase.
// Epilogue atomically accumulates S2/X1 partials into S2X1 (s2red kernel deleted).
__global__ __launch_bounds__(256, 4) void rgcn_fused_k(
    const int* __restrict__ blkcnt, const int* __restrict__ blkbuf,
    const __bf16* __restrict__ xb, const __bf16* __restrict__ wf,
    const float* __restrict__ b1, const float* __restrict__ wsum,
    float* __restrict__ S2X1)
{
    __shared__ __attribute__((aligned(16))) __bf16 buf[64 * SPAD]; // 17.4 KB: Et(16KB)/Atile/red, time-shared
    __shared__ int   loffs[TM * NR + 1];
    __shared__ int   lcnt[TM * NR];
    __shared__ int   cursor[TM * NR];
    __shared__ float invl[TM * NR];
    __shared__ float wsl[NR][TM];
    __shared__ int   pkd[CAP];          // heads, CSR-sorted by j2 (term-major)
    const int tid = threadIdx.x;
    const int wave = tid >> 6, lane = tid & 63, quad = lane >> 4;
    const int slot = tid >> 4, sl = tid & 15;   // 16 loader slots x 16 lanes (8 cols each)
    const int tbase = blockIdx.x * TM;
    const int mrow = lane & 15;

    // ---- local CSR build (j2 = term*32 + trow) ----
    int n = blkcnt[blockIdx.x * 16];
    if (n > CAP) n = CAP;
    const int* gbuf = blkbuf + (size_t)blockIdx.x * CAP;
    lcnt[tid] = 0;
    __syncthreads();
    int pk0 = -1, pk1 = -1, pk2 = -1, pk3 = -1;
    if (tid < n)       { pk0 = gbuf[tid];       atomicAdd(&lcnt[pk0 >> 17], 1); }
    if (tid + 256 < n) { pk1 = gbuf[tid + 256]; atomicAdd(&lcnt[pk1 >> 17], 1); }
    if (tid + 512 < n) { pk2 = gbuf[tid + 512]; atomicAdd(&lcnt[pk2 >> 17], 1); }
    if (tid + 768 < n) { pk3 = gbuf[tid + 768]; atomicAdd(&lcnt[pk3 >> 17], 1); }
    __syncthreads();
    int v = lcnt[tid];
    int* ss = reinterpret_cast<int*>(buf);
    ss[tid] = v;
    __syncthreads();
#pragma unroll
    for (int off = 1; off < 256; off <<= 1) {
        int val = (tid >= off) ? ss[tid - off] : 0;
        __syncthreads();
        if (tid >= off) ss[tid] += val;
        __syncthreads();
    }
    loffs[tid + 1] = ss[tid];            // inclusive
    if (tid == 0) loffs[0] = 0;
    cursor[tid] = ss[tid] - v;           // exclusive
    invl[tid] = 1.0f / (float)(v > 1 ? v : 1);
    {
        int rr = tid >> 5, nn = tbase + (tid & 31);
        wsl[rr][tid & 31] = (nn < NN) ? wsum[rr * NN + nn] : 0.f;
    }
    __syncthreads();
    if (pk0 >= 0) { int p = atomicAdd(&cursor[pk0 >> 17], 1); pkd[p] = pk0 & 0x1FFFF; }
    if (pk1 >= 0) { int p = atomicAdd(&cursor[pk1 >> 17], 1); pkd[p] = pk1 & 0x1FFFF; }
    if (pk2 >= 0) { int p = atomicAdd(&cursor[pk2 >> 17], 1); pkd[p] = pk2 & 0x1FFFF; }
    if (pk3 >= 0) { int p = atomicAdd(&cursor[pk3 >> 17], 1); pkd[p] = pk3 & 0x1FFFF; }
    __syncthreads();

    floatx4 C[4];
#pragma unroll
    for (int i = 0; i < 4; ++i) C[i] = (floatx4)0.f;
    const int arow = (wave & 1) * 16 + mrow;          // W-phase wave row-strip
    const int ntg0 = (wave >> 1) * 4;                 // W-phase wave col-strip (4 nt each)
    const int rt0  = (wave & 1) * 2;                  // P-phase: 2 row-tiles (32 rows)
    const int cbt  = (wave >> 1) * 4;                 // P-phase: 4 col-tiles (64 cols)
    const int prow0 = rt0 * 16 + mrow;                // lane's P rows for the 2 row-tiles
    const int prow1 = prow0 + 16;
    const int e0q = quad * 8;                         // lane's k-subrange base

    // chunk staging: thread (slot,sl) owns edges {2s, 2s+1, 2s+32, 2s+33}, cols sl*8..+7
    bf16x8 st[4];
    auto LOADCHUNK = [&](int base, int end) {
#pragma unroll
        for (int i = 0; i < 4; ++i) {
            int el = 2 * slot + (i & 1) + 32 * (i >> 1);
            int pos = base + el;
            if (pos < end) {
                int he = pkd[pos];                    // slot-uniform -> LDS broadcast
                st[i] = *reinterpret_cast<const bf16x8*>(xb + (size_t)he * DIM + sl * 8);
            } else {
#pragma unroll
                for (int j = 0; j < 8; ++j) st[i][j] = (__bf16)0.f;  // zero-fill: Et fully defined
            }
        }
    };
    auto WRITECHUNK = [&]() {
#pragma unroll
        for (int p = 0; p < 2; ++p) {
            const ushort8 lo = reinterpret_cast<const ushort8&>(st[2 * p]);
            const ushort8 hi = reinterpret_cast<const ushort8&>(st[2 * p + 1]);
            int e  = 2 * slot + 32 * p;
            int swz = (((e >> 3) ^ (sl & 7)) << 3) + (e & 7);   // col>>3 == sl
#pragma unroll
            for (int k = 0; k < 8; ++k) {
                int idx = (sl * 8 + k) * 64 + swz;
                *reinterpret_cast<unsigned int*>(&buf[idx]) =
                    (unsigned int)lo[k] | ((unsigned int)hi[k] << 16);
            }
        }
    };

    // prologue: prefetch chunk 0 of tp 0 (pkd ready; buf free after scan)
    LOADCHUNK(loffs[0], loffs[64]);

    for (int tp = 0; tp < 4; ++tp) {
        const int j64 = tp * 64;
        const int tpS = loffs[j64], tpE = loffs[j64 + 64];
        const int NC = (tpE - tpS + 63) >> 6;
        const int s0a = loffs[j64 + prow0], s1a = loffs[j64 + prow0 + 1];
        const int s0b = loffs[j64 + prow1], s1b = loffs[j64 + prow1 + 1];
        floatx4 Acc[2][4];
#pragma unroll
        for (int i = 0; i < 2; ++i)
#pragma unroll
            for (int j = 0; j < 4; ++j) Acc[i][j] = (floatx4)0.f;

        if (NC == 0) {
            if (tp < 3) LOADCHUNK(loffs[j64 + 64], loffs[j64 + 128]);
        } else {
            for (int c = 0; c < NC; ++c) {
                int Cb = tpS + c * 64;
                WRITECHUNK();                             // consumes st (reg WAR is free)
                if (c + 1 < NC)   LOADCHUNK(Cb + 64, tpE);
                else if (tp < 3)  LOADCHUNK(loffs[j64 + 64], loffs[j64 + 128]);
                __syncthreads();                          // Et visible
                // staircase intervals, clamped to this chunk
                int loA = s0a - Cb; loA = loA < 0 ? 0 : (loA > 64 ? 64 : loA);
                int hiA = s1a - Cb; hiA = hiA < 0 ? 0 : (hiA > 64 ? 64 : hiA);
                int loB = s0b - Cb; loB = loB < 0 ? 0 : (loB > 64 ? 64 : loB);
                int hiB = s1b - Cb; hiB = hiB < 0 ? 0 : (hiB > 64 ? 64 : hiB);
                const __bf16 ONE = (__bf16)1.0f, ZER = (__bf16)0.0f;
#pragma unroll
                for (int s = 0; s < 2; ++s) {
                    bf16x8 afA, afB;
#pragma unroll
                    for (int j = 0; j < 8; ++j) {
                        int e = s * 32 + e0q + j;
                        afA[j] = (e >= loA && e < hiA) ? ONE : ZER;
                        afB[j] = (e >= loB && e < hiB) ? ONE : ZER;
                    }
#pragma unroll
                    for (int ct = 0; ct < 4; ++ct) {
                        int colB = (cbt + ct) * 16 + mrow;
                        int idxB = colB * 64 + (((s * 4 + quad) ^ ((colB >> 3) & 7)) << 3);
                        bf16x8 bfr = *reinterpret_cast<const bf16x8*>(&buf[idxB]);
                        Acc[0][ct] = __builtin_amdgcn_mfma_f32_16x16x32_bf16(afA, bfr, Acc[0][ct], 0, 0, 0);
                        Acc[1][ct] = __builtin_amdgcn_mfma_f32_16x16x32_bf16(afB, bfr, Acc[1][ct], 0, 0, 0);
                    }
                }
                __syncthreads();                          // Et reusable
            }
        }

        // ---- Acc -> Atile: scale by 1/cnt in f32, cvt bf16; C-layout row=(quad*4+i), col=mrow ----
#pragma unroll
        for (int rt = 0; rt < 2; ++rt) {
#pragma unroll
            for (int i = 0; i < 4; ++i) {
                int g = (rt0 + rt) * 16 + quad * 4 + i;
                float iv = invl[j64 + g];
#pragma unroll
                for (int ct = 0; ct < 4; ++ct)
                    buf[g * SPAD + (cbt + ct) * 16 + mrow] = (__bf16)(Acc[rt][ct][i] * iv);
            }
        }
        __syncthreads();

        // ---- MFMA both terms of the pair vs W (R2-proven pattern; Atile stride SPAD) ----
#pragma unroll
        for (int u = 0; u < 2; ++u) {
            const __bf16* wterm = wf + (size_t)(tp * 2 + u) * 2048 * 8;
#pragma unroll
            for (int s = 0; s < 4; ++s) {
                bf16x8 af = *reinterpret_cast<const bf16x8*>(
                    &buf[(u * 32 + arow) * SPAD + s * 32 + quad * 8]);
#pragma unroll
                for (int nt = 0; nt < 4; ++nt) {
                    bf16x8 bfv = *reinterpret_cast<const bf16x8*>(
                        wterm + (size_t)((s * 8 + ntg0 + nt) * 64 + lane) * 8);
                    C[nt] = __builtin_amdgcn_mfma_f32_16x16x32_bf16(af, bfv, C[nt], 0, 0, 0);
                }
            }
        }
        __syncthreads();                                  // Atile free -> Et next tp
    }

    // ---- root term: af rows read directly from global xb (no LDS staging) ----
    {
        const __bf16* wterm = wf + (size_t)8 * 2048 * 8;
        int node = tbase + arow;
#pragma unroll
        for (int s = 0; s < 4; ++s) {
            bf16x8 af;
            if (node < NN) {
                af = *reinterpret_cast<const bf16x8*>(xb + (size_t)node * DIM + s * 32 + quad * 8);
            } else {
#pragma unroll
                for (int j = 0; j < 8; ++j) af[j] = (__bf16)0.f;
            }
#pragma unroll
            for (int nt = 0; nt < 4; ++nt) {
                bf16x8 bfv = *reinterpret_cast<const bf16x8*>(
                    wterm + (size_t)((s * 8 + ntg0 + nt) * 64 + lane) * 8);
                C[nt] = __builtin_amdgcn_mfma_f32_16x16x32_bf16(af, bfv, C[nt], 0, 0, 0);
            }
        }
    }

    // ---- epilogue: bias + relu in-register, fused S2/X1 partials -> GLOBAL ATOMIC accumulate ----
    float* red = reinterpret_cast<float*>(buf);   // [4][576] = 9.2 KB <= 17.4 KB
    const int rowl0 = (wave & 1) * 16 + quad * 4;
    const int colc = mrow;
#pragma unroll
    for (int nt = 0; nt < 4; ++nt) {
        float badd = b1[ntg0 * 16 + nt * 16 + colc];
#pragma unroll
        for (int i = 0; i < 4; ++i) C[nt][i] = fmaxf(C[nt][i] + badd, 0.f);
    }
    float rmask[4];
#pragma unroll
    for (int i = 0; i < 4; ++i) rmask[i] = (tbase + rowl0 + i < NN) ? 1.f : 0.f;
#pragma unroll
    for (int nt = 0; nt < 4; ++nt) {
        float p = rmask[0] * C[nt][0] + rmask[1] * C[nt][1] + rmask[2] * C[nt][2] + rmask[3] * C[nt][3];
        p += __shfl_xor(p, 16);
        p += __shfl_xor(p, 32);
        if (quad == 0) red[wave * 576 + nt * 16 + colc] = p;
    }
#pragma unroll
    for (int rr = 0; rr < NR; ++rr) {
        float w0 = wsl[rr][rowl0], w1 = wsl[rr][rowl0 + 1];
        float w2 = wsl[rr][rowl0 + 2], w3 = wsl[rr][rowl0 + 3];
#pragma unroll
        for (int nt = 0; nt < 4; ++nt) {
            float p = w0 * C[nt][0] + w1 * C[nt][1] + w2 * C[nt][2] + w3 * C[nt][3];
            p += __shfl_xor(p, 16);
            p += __shfl_xor(p, 32);
            if (quad == 0) red[wave * 576 + 64 + rr * 64 + nt * 16 + colc] = p;
        }
    }
    __syncthreads();
    for (int j = tid; j < 1152; j += 256) {
        int rr = j >> 7, c = j & 127;          // rr==8 -> X1
        int u = c >> 6, cc = c & 63;
        int o = (rr < 8) ? (64 + rr * 64 + cc) : cc;
        atomicAdd(&S2X1[j], red[(u * 2) * 576 + o] + red[(u * 2 + 1) * 576 + o]);
    }
}

// ---------------- final: out = (S2.W2 + X1.root2)/N + b2  (1024 thr, 8-way split, 2 ILP chains) ----------------
__global__ __launch_bounds__(1024) void final_k(
    const float* __restrict__ S2X1, const float* __restrict__ W2,
    const float* __restrict__ root2, const float* __restrict__ b2, float* __restrict__ out)
{
    __shared__ float red[1024];
    const int o = threadIdx.x & 127, c = threadIdx.x >> 7;  // 8 chunks of 144 terms
    float s = 0.f, s2 = 0.f;
#pragma unroll 2
    for (int j = c * 144; j < (c + 1) * 144; j += 2) {
        float v0 = S2X1[j], v1 = S2X1[j + 1];
        float w0 = (j < 1024) ? W2[(size_t)j * DIM + o] : root2[(size_t)(j - 1024) * DIM + o];
        float w1 = (j + 1 < 1024) ? W2[(size_t)(j + 1) * DIM + o] : root2[(size_t)(j + 1 - 1024) * DIM + o];
        s += v0 * w0; s2 += v1 * w1;
    }
    red[threadIdx.x] = s + s2;
    __syncthreads();
    if (c == 0) {
        float tot = 0.f;
#pragma unroll
        for (int k = 0; k < 8; ++k) tot += red[o + 128 * k];
        out[o] = tot * (1.0f / NN) + b2[o];
    }
}

extern "C" void kernel_launch(void* const* d_in, const int* in_sizes, int n_in,
                              void* d_out, int out_size, void* d_ws, size_t ws_size,
                              hipStream_t stream)
{
    const int*   h     = (const int*)d_in[0];
    const int*   r     = (const int*)d_in[1];
    const int*   t     = (const int*)d_in[2];
    const float* x_emb = (const float*)d_in[3];
    const float* W1    = (const float*)d_in[4];
    const float* root1 = (const float*)d_in[5];
    const float* b1    = (const float*)d_in[6];
    const float* W2    = (const float*)d_in[7];
    const float* root2 = (const float*)d_in[8];
    const float* b2    = (const float*)d_in[9];

    float* ws     = (float*)d_ws;
    int*   cnt    = (int*)(ws + OFF_CNT);
    float* wsum   = ws + OFF_WSUM;
    float* S2     = ws + OFF_S2;      // 1024 S2 + 128 X1 contiguous
    int*   blkcnt = (int*)(ws + OFF_BCNT);
    int*   blkbuf = (int*)(ws + OFF_BBUF);
    __bf16* xb    = (__bf16*)(ws + OFF_XB);
    __bf16* wf    = (__bf16*)(ws + OFF_WF);

    // zero cnt + wsum + S2X1 + blkcnt (ws re-poisoned to 0xAA before every timed launch)
    hipMemsetAsync(ws, 0, (size_t)826160 * sizeof(float), stream);

    // merged cast + weight-frag + count + bucket-assign (one edge pass, term-major key)
    prep_k<<<1600, 256, 0, stream>>>(x_emb, xb, W1, root1, wf, h, r, t, cnt, blkcnt, blkbuf);

    // wsum: inv derived from cnt directly (no scan, no CSR)
    wsum_k<<<782, 256, 0, stream>>>(h, r, t, cnt, wsum);

    // fused layer 1 + layer-2 partials: staircase-P MFMA aggregation, atomic S2 finish
    rgcn_fused_k<<<NB, 256, 0, stream>>>(blkcnt, blkbuf, xb, wf, b1, wsum, S2);

    final_k<<<1, 1024, 0, stream>>>(S2, W2, root2, b2, (float*)d_out);
}

// Round 4
// 284.230 us; speedup vs baseline: 1.5247x; 1.5247x over previous
//
#include <hip/hip_runtime.h>
#include <hip/hip_bf16.h>

#define NN 50000
#define NR 8
#define DIM 128
#define NE 800000
#define TM 32     // targets per block
#define PAD 136   // A-tile row stride in bf16 (128 + 8): R0-proven banking
#define CAP 1024  // per-block bucket capacity (mean 512, Poisson -> overflow prob ~0; guarded)
#define NB 1563   // ceil(NN/TM)

using floatx4 = __attribute__((ext_vector_type(4))) float;
using bf16x8  = __attribute__((ext_vector_type(8))) __bf16;

// ---------------- workspace layout (in floats) ----------------
// zeroed region: [0, 426160) = wsum + S2X1 + blkcnt   (cnt array DELETED)
#define OFF_WSUM  0u         // 400000: wsum[r*NN+h] fp32 atomic accum
#define OFF_S2    400000u    // 1152: S2[1024] + X1[128]
#define OFF_BCNT  401152u    // 1563*16 ints: per-block bucket counters (64B stride)
#define OFF_BBUF  426160u    // 1563*1024 ints: per-block edge buckets, pk = (lseg<<17)|head
#define OFF_XB    2026672u   // 6.4M bf16: x_emb in bf16 (16B aligned)
#define OFF_WF    5226672u   // 9*2048*8 bf16: weights in MFMA frag order
#define OFF_S2P   5300400u   // NB*1152: per-block S2/X1 partials
// total 7,100,976 floats = 28.4 MB

// ---------------- merged prep: bf16 cast + weight frags + bucket assign (cnt atomic DELETED) ----------------
// bucket key TARGET-MAJOR (R0): lseg = (te&31)*NR + re  -> pk = (lseg<<17)|he
__global__ __launch_bounds__(256) void prep_k(
    const float* __restrict__ x, __bf16* __restrict__ xb,
    const float* __restrict__ W1, const float* __restrict__ root1, __bf16* __restrict__ wf,
    const int* __restrict__ h, const int* __restrict__ r, const int* __restrict__ t,
    int* __restrict__ blkcnt, int* __restrict__ blkbuf)
{
    const int gid = blockIdx.x * 256 + threadIdx.x;
    const int nthr = gridDim.x * 256;

    if (gid < 9 * 2048) {
        int mat = gid >> 11, idx = gid & 2047;
        const float* B = (mat < 8) ? (W1 + (size_t)mat * DIM * DIM) : root1;
        int lt = idx & 63, fid = idx >> 6;
        int s = fid >> 3, nt = fid & 7;
        int n = nt * 16 + (lt & 15);
        int kb = s * 32 + (lt >> 4) * 8;
        bf16x8 v;
#pragma unroll
        for (int j = 0; j < 8; ++j) v[j] = (__bf16)B[(kb + j) * DIM + n];
        *reinterpret_cast<bf16x8*>(wf + ((size_t)mat * 2048 + idx) * 8) = v;
    }
    for (int i = gid; i < NN * DIM / 4; i += nthr) {
        int base = i * 4;
        float4 v = *reinterpret_cast<const float4*>(x + base);
        __bf16 o[4] = {(__bf16)v.x, (__bf16)v.y, (__bf16)v.z, (__bf16)v.w};
        *reinterpret_cast<uint2*>(xb + base) = *reinterpret_cast<uint2*>(o);
    }
    // edge loop: bucket append only (one global atomic per edge)
    for (int i = gid; i < NE / 4; i += nthr) {
        int base = i * 4;
        int4 hv = *reinterpret_cast<const int4*>(h + base);
        int4 rv = *reinterpret_cast<const int4*>(r + base);
        int4 tv = *reinterpret_cast<const int4*>(t + base);
#pragma unroll
        for (int j = 0; j < 4; ++j) {
            int te = (j == 0) ? tv.x : (j == 1) ? tv.y : (j == 2) ? tv.z : tv.w;
            int re = (j == 0) ? rv.x : (j == 1) ? rv.y : (j == 2) ? rv.z : rv.w;
            int he = (j == 0) ? hv.x : (j == 1) ? hv.y : (j == 2) ? hv.z : hv.w;
            int blk = te >> 5;
            int pos = atomicAdd(&blkcnt[blk * 16], 1);
            if (pos < CAP) blkbuf[blk * CAP + pos] = ((((te & 31) * NR) + re) << 17) | he;
        }
    }
}

// ---------------- wsum: bucket-based (replaces h/r/t re-read + 800k random cnt gathers) ----------------
// Each block: read its bucket (4 strided coalesced loads/thread), LDS histogram over the 256
// local segments (proven pattern from fused's CSR build), then atomicAdd 1/c per edge.
// Counts from the bucket == global cnt (bucket holds every edge of these targets; CAP never hit).
__global__ __launch_bounds__(256) void wsum_k(
    const int* __restrict__ blkcnt, const int* __restrict__ blkbuf, float* __restrict__ wsum)
{
    __shared__ int   lcnt[TM * NR];
    __shared__ float linv[TM * NR];
    const int tid = threadIdx.x;
    int n = blkcnt[blockIdx.x * 16];
    if (n > CAP) n = CAP;
    const int* gbuf = blkbuf + (size_t)blockIdx.x * CAP;
    lcnt[tid] = 0;
    __syncthreads();
    int pk0 = -1, pk1 = -1, pk2 = -1, pk3 = -1;
    if (tid < n)       { pk0 = gbuf[tid];       atomicAdd(&lcnt[pk0 >> 17], 1); }
    if (tid + 256 < n) { pk1 = gbuf[tid + 256]; atomicAdd(&lcnt[pk1 >> 17], 1); }
    if (tid + 512 < n) { pk2 = gbuf[tid + 512]; atomicAdd(&lcnt[pk2 >> 17], 1); }
    if (tid + 768 < n) { pk3 = gbuf[tid + 768]; atomicAdd(&lcnt[pk3 >> 17], 1); }
    __syncthreads();
    int c = lcnt[tid];
    linv[tid] = 1.0f / (float)(c > 1 ? c : 1);
    __syncthreads();
    // lseg = pk>>17 = (t&31)*8 + r  ->  r = lseg & 7 ; h = pk & 0x1FFFF
    if (pk0 >= 0) atomicAdd(&wsum[(size_t)((pk0 >> 17) & 7) * NN + (pk0 & 0x1FFFF)], linv[pk0 >> 17]);
    if (pk1 >= 0) atomicAdd(&wsum[(size_t)((pk1 >> 17) & 7) * NN + (pk1 & 0x1FFFF)], linv[pk1 >> 17]);
    if (pk2 >= 0) atomicAdd(&wsum[(size_t)((pk2 >> 17) & 7) * NN + (pk2 & 0x1FFFF)], linv[pk2 >> 17]);
    if (pk3 >= 0) atomicAdd(&wsum[(size_t)((pk3 >> 17) & 7) * NN + (pk3 & 0x1FFFF)], linv[pk3 >> 17]);
}

// ---------------- fused layer 1 + layer-2 partials: local CSR + R14 depth-2 walk (R0 EXACT) ----------------
__global__ __launch_bounds__(256, 4) void rgcn_fused_k(
    const int* __restrict__ blkcnt, const int* __restrict__ blkbuf,
    const __bf16* __restrict__ xb, const __bf16* __restrict__ wf,
    const float* __restrict__ b1, const float* __restrict__ wsum,
    float* __restrict__ S2P)
{
    __shared__ __attribute__((aligned(16))) __bf16 Atile[2][TM * PAD];  // 17.4 KB (scan temp + red reuse)
    __shared__ int   loffs[TM * NR + 1];
    __shared__ int   lcnt[TM * NR];
    __shared__ int   cursor[TM * NR];
    __shared__ float invl[TM * NR];
    __shared__ float wsl[NR][TM];
    __shared__ int   pkd[CAP];          // heads, sorted by local segment
    const int tid = threadIdx.x;
    const int wave = tid >> 6, lane = tid & 63, quad = lane >> 4;
    const int slot = tid >> 4, sl = tid & 15;   // 16 gather slots x 16 lanes
    const int tbase = blockIdx.x * TM;

    // ---- local CSR build ----
    int n = blkcnt[blockIdx.x * 16];
    if (n > CAP) n = CAP;
    const int* gbuf = blkbuf + (size_t)blockIdx.x * CAP;
    lcnt[tid] = 0;
    __syncthreads();
    int pk0 = -1, pk1 = -1, pk2 = -1, pk3 = -1;
    if (tid < n)       { pk0 = gbuf[tid];       atomicAdd(&lcnt[pk0 >> 17], 1); }
    if (tid + 256 < n) { pk1 = gbuf[tid + 256]; atomicAdd(&lcnt[pk1 >> 17], 1); }
    if (tid + 512 < n) { pk2 = gbuf[tid + 512]; atomicAdd(&lcnt[pk2 >> 17], 1); }
    if (tid + 768 < n) { pk3 = gbuf[tid + 768]; atomicAdd(&lcnt[pk3 >> 17], 1); }
    __syncthreads();
    int v = lcnt[tid];
    int* ss = reinterpret_cast<int*>(&Atile[0][0]);
    ss[tid] = v;
    __syncthreads();
#pragma unroll
    for (int off = 1; off < 256; off <<= 1) {
        int val = (tid >= off) ? ss[tid - off] : 0;
        __syncthreads();
        if (tid >= off) ss[tid] += val;
        __syncthreads();
    }
    loffs[tid + 1] = ss[tid];            // inclusive
    if (tid == 0) loffs[0] = 0;
    cursor[tid] = ss[tid] - v;           // exclusive
    invl[tid] = 1.0f / (float)(v > 1 ? v : 1);
    if (tid < NR * TM) {                 // (always true; kept for clarity)
        int rr = tid >> 5, nn = tbase + (tid & 31);
        wsl[rr][tid & 31] = (nn < NN) ? wsum[rr * NN + nn] : 0.f;
    }
    __syncthreads();
    if (pk0 >= 0) { int p = atomicAdd(&cursor[pk0 >> 17], 1); pkd[p] = pk0 & 0x1FFFF; }
    if (pk1 >= 0) { int p = atomicAdd(&cursor[pk1 >> 17], 1); pkd[p] = pk1 & 0x1FFFF; }
    if (pk2 >= 0) { int p = atomicAdd(&cursor[pk2 >> 17], 1); pkd[p] = pk2 & 0x1FFFF; }
    if (pk3 >= 0) { int p = atomicAdd(&cursor[pk3 >> 17], 1); pkd[p] = pk3 & 0x1FFFF; }
    __syncthreads();

    floatx4 C[4];
#pragma unroll
    for (int i = 0; i < 4; ++i) C[i] = (floatx4)0.f;
    const int arow = (wave & 1) * 16 + (lane & 15);   // wave row-strip
    const int ntg0 = (wave >> 1) * 4;                 // wave col-strip (4 nt each)

    // ---- 4 term-pairs: 4 depth-2-pipelined walks (2 rows x 2 terms), 2 A-tiles (R14 exact) ----
    for (int tp = 0; tp < 4; ++tp) {
        int st[4], ln[4];
        float a[4][8];
#pragma unroll
        for (int q = 0; q < 4; ++q) {
            int j = (slot + (q >> 1) * 16) * 8 + tp * 2 + (q & 1);
            st[q] = loffs[j];
            ln[q] = loffs[j + 1] - loffs[j];
#pragma unroll
            for (int k = 0; k < 8; ++k) a[q][k] = 0.f;
        }
        int mx = max(max(ln[0], ln[1]), max(ln[2], ln[3]));
        if (mx > 0) {
            bf16x8 ycur[4];
#pragma unroll
            for (int q = 0; q < 4; ++q) {
                if (0 < ln[q]) {
                    int he = pkd[st[q]];
                    ycur[q] = *reinterpret_cast<const bf16x8*>(xb + (size_t)he * DIM + sl * 8);
                }
            }
            for (int p = 0; p < mx; ++p) {
                bf16x8 ynext[4];
#pragma unroll
                for (int q = 0; q < 4; ++q) {
                    if (p + 1 < ln[q]) {
                        int he = pkd[st[q] + p + 1];
                        ynext[q] = *reinterpret_cast<const bf16x8*>(xb + (size_t)he * DIM + sl * 8);
                    }
                }
#pragma unroll
                for (int q = 0; q < 4; ++q) {
                    if (p < ln[q]) {
#pragma unroll
                        for (int k = 0; k < 8; ++k) a[q][k] += (float)ycur[q][k];
                    }
                }
#pragma unroll
                for (int q = 0; q < 4; ++q) ycur[q] = ynext[q];
            }
        }
#pragma unroll
        for (int q = 0; q < 4; ++q) {
            int trow = slot + (q >> 1) * 16;
            float sc = invl[trow * 8 + tp * 2 + (q & 1)];
            bf16x8 out;
#pragma unroll
            for (int k = 0; k < 8; ++k) out[k] = (__bf16)(a[q][k] * sc);
            *reinterpret_cast<bf16x8*>(&Atile[q & 1][trow * PAD + sl * 8]) = out;
        }
        __syncthreads();
#pragma unroll
        for (int u = 0; u < 2; ++u) {
            const __bf16* wterm = wf + (size_t)(tp * 2 + u) * 2048 * 8;
#pragma unroll
            for (int s = 0; s < 4; ++s) {
                bf16x8 af = *reinterpret_cast<const bf16x8*>(&Atile[u][arow * PAD + s * 32 + quad * 8]);
#pragma unroll
                for (int nt = 0; nt < 4; ++nt) {
                    bf16x8 bf = *reinterpret_cast<const bf16x8*>(
                        wterm + (size_t)((s * 8 + ntg0 + nt) * 64 + lane) * 8);
                    C[nt] = __builtin_amdgcn_mfma_f32_16x16x32_bf16(af, bf, C[nt], 0, 0, 0);
                }
            }
        }
        __syncthreads();
    }

    // ---- root term: A row = xb[t] ----
#pragma unroll
    for (int i = 0; i < 2; ++i) {
        int trow = slot + i * 16;
        int t = tbase + trow;
        bf16x8 out;
        if (t < NN) {
            out = *reinterpret_cast<const bf16x8*>(xb + (size_t)t * DIM + sl * 8);
        } else {
#pragma unroll
            for (int j = 0; j < 8; ++j) out[j] = (__bf16)0.f;
        }
        *reinterpret_cast<bf16x8*>(&Atile[0][trow * PAD + sl * 8]) = out;
    }
    __syncthreads();
    {
        const __bf16* wterm = wf + (size_t)8 * 2048 * 8;
#pragma unroll
        for (int s = 0; s < 4; ++s) {
            bf16x8 af = *reinterpret_cast<const bf16x8*>(&Atile[0][arow * PAD + s * 32 + quad * 8]);
#pragma unroll
            for (int nt = 0; nt < 4; ++nt) {
                bf16x8 bf = *reinterpret_cast<const bf16x8*>(
                    wterm + (size_t)((s * 8 + ntg0 + nt) * 64 + lane) * 8);
                C[nt] = __builtin_amdgcn_mfma_f32_16x16x32_bf16(af, bf, C[nt], 0, 0, 0);
            }
        }
    }
    __syncthreads();   // Atile dead -> reuse as reduction scratch

    // ---- epilogue: bias + relu in-register, fused S2/X1 block partials (R14 exact) ----
    float* red = reinterpret_cast<float*>(&Atile[0][0]);   // [4][576] = 9.2 KB
    const int rowl0 = (wave & 1) * 16 + quad * 4;
    const int colc = lane & 15;
#pragma unroll
    for (int nt = 0; nt < 4; ++nt) {
        float badd = b1[ntg0 * 16 + nt * 16 + colc];
#pragma unroll
        for (int i = 0; i < 4; ++i) C[nt][i] = fmaxf(C[nt][i] + badd, 0.f);
    }
    float rmask[4];
#pragma unroll
    for (int i = 0; i < 4; ++i) rmask[i] = (tbase + rowl0 + i < NN) ? 1.f : 0.f;
#pragma unroll
    for (int nt = 0; nt < 4; ++nt) {
        float p = rmask[0] * C[nt][0] + rmask[1] * C[nt][1] + rmask[2] * C[nt][2] + rmask[3] * C[nt][3];
        p += __shfl_xor(p, 16);
        p += __shfl_xor(p, 32);
        if (quad == 0) red[wave * 576 + nt * 16 + colc] = p;
    }
#pragma unroll
    for (int rr = 0; rr < NR; ++rr) {
        float w0 = wsl[rr][rowl0], w1 = wsl[rr][rowl0 + 1];
        float w2 = wsl[rr][rowl0 + 2], w3 = wsl[rr][rowl0 + 3];
#pragma unroll
        for (int nt = 0; nt < 4; ++nt) {
            float p = w0 * C[nt][0] + w1 * C[nt][1] + w2 * C[nt][2] + w3 * C[nt][3];
            p += __shfl_xor(p, 16);
            p += __shfl_xor(p, 32);
            if (quad == 0) red[wave * 576 + 64 + rr * 64 + nt * 16 + colc] = p;
        }
    }
    __syncthreads();
    for (int j = tid; j < 1152; j += 256) {
        int rr = j >> 7, c = j & 127;          // rr==8 -> X1
        int u = c >> 6, cc = c & 63;
        int o = (rr < 8) ? (64 + rr * 64 + cc) : cc;
        S2P[(size_t)blockIdx.x * 1152 + j] = red[(u * 2) * 576 + o] + red[(u * 2 + 1) * 576 + o];
    }
}

// ---------------- reduce S2P[NB][1152] -> S2X1[1152] (atomic finish, 63 stripes of 25; R2-proven) ----------------
__global__ void s2red_k(const float* __restrict__ S2P, float* __restrict__ S2X1) {
    int cb = blockIdx.x % 5, stripe = blockIdx.x / 5;
    int c = cb * 256 + threadIdx.x;
    if (c >= 1152) return;
    int b0 = stripe * 25, b1 = min(NB, b0 + 25);
    if (b0 >= NB) return;
    float s0 = 0.f, s1 = 0.f;
    int b = b0;
    for (; b + 1 < b1; b += 2) {
        s0 += S2P[(size_t)b * 1152 + c];
        s1 += S2P[(size_t)(b + 1) * 1152 + c];
    }
    if (b < b1) s0 += S2P[(size_t)b * 1152 + c];
    atomicAdd(&S2X1[c], s0 + s1);
}

// ---------------- final: out = (S2.W2 + X1.root2)/N + b2  -- 9 blocks x 128-term stripes, atomic finish ----------------
__global__ __launch_bounds__(256) void final_k(
    const float* __restrict__ S2X1, const float* __restrict__ W2,
    const float* __restrict__ root2, const float* __restrict__ b2, float* __restrict__ out)
{
    __shared__ float red[256];
    const int o = threadIdx.x & 127, half = threadIdx.x >> 7;
    const int jb = blockIdx.x * 128 + half * 64;
    float s = 0.f;
#pragma unroll 2
    for (int k = 0; k < 64; ++k) {
        int j = jb + k;
        float v = S2X1[j];
        float w = (j < 1024) ? W2[(size_t)j * DIM + o] : root2[(size_t)(j - 1024) * DIM + o];
        s += v * w;
    }
    red[threadIdx.x] = s;
    __syncthreads();
    if (half == 0) {
        float add = (red[o] + red[o + 128]) * (1.0f / NN);
        if (blockIdx.x == 0) add += b2[o];
        atomicAdd(&out[o], add);
    }
}

extern "C" void kernel_launch(void* const* d_in, const int* in_sizes, int n_in,
                              void* d_out, int out_size, void* d_ws, size_t ws_size,
                              hipStream_t stream)
{
    const int*   h     = (const int*)d_in[0];
    const int*   r     = (const int*)d_in[1];
    const int*   t     = (const int*)d_in[2];
    const float* x_emb = (const float*)d_in[3];
    const float* W1    = (const float*)d_in[4];
    const float* root1 = (const float*)d_in[5];
    const float* b1    = (const float*)d_in[6];
    const float* W2    = (const float*)d_in[7];
    const float* root2 = (const float*)d_in[8];
    const float* b2    = (const float*)d_in[9];

    float* ws     = (float*)d_ws;
    float* wsum   = ws + OFF_WSUM;
    float* S2     = ws + OFF_S2;      // 1024 S2 + 128 X1 contiguous
    int*   blkcnt = (int*)(ws + OFF_BCNT);
    int*   blkbuf = (int*)(ws + OFF_BBUF);
    __bf16* xb    = (__bf16*)(ws + OFF_XB);
    __bf16* wf    = (__bf16*)(ws + OFF_WF);
    float* S2P    = ws + OFF_S2P;

    // zero wsum + S2X1 + blkcnt (1.7 MB, was 3.3); out zeroed for final's atomic finish
    hipMemsetAsync(ws, 0, (size_t)426160 * sizeof(float), stream);
    hipMemsetAsync(d_out, 0, 128 * sizeof(float), stream);

    // merged cast + weight-frag + bucket-assign (one edge pass, one atomic per edge)
    prep_k<<<1600, 256, 0, stream>>>(x_emb, xb, W1, root1, wf, h, r, t, blkcnt, blkbuf);

    // wsum from buckets: no h/r/t re-read, no random cnt gather
    wsum_k<<<NB, 256, 0, stream>>>(blkcnt, blkbuf, wsum);

    // fused layer 1 + layer-2 partials: R0-exact local CSR + depth-2 walk
    rgcn_fused_k<<<NB, 256, 0, stream>>>(blkcnt, blkbuf, xb, wf, b1, wsum, S2P);

    s2red_k<<<315, 256, 0, stream>>>(S2P, S2);
    final_k<<<9, 256, 0, stream>>>(S2, W2, root2, b2, (float*)d_out);
}